// Round 3
// baseline (912.413 us; speedup 1.0000x reference)
//
#include <hip/hip_runtime.h>

#define N_NODES 65536
#define N_EDGES 1048576
#define B_GRAPHS 32
#define NPG     2048
#define EPS_GN  1e-5f
#define SLOPE   0.01f
#define NBUCKET 256    // coarse buckets (dst>>8), 256 nodes each

// ---------------- coarse dst-bucket histogram (LDS-privatized) ----------------
__global__ __launch_bounds__(256) void coarse_hist(const int4* __restrict__ dst4,
                                                   int* __restrict__ coarse) {
    __shared__ int lh[256];
    int tid = threadIdx.x;
    lh[tid] = 0;
    __syncthreads();
#pragma unroll
    for (int k = 0; k < 16; ++k) {
        int4 v = dst4[blockIdx.x * 4096 + k * 256 + tid];
        atomicAdd(&lh[v.x >> 8], 1);
        atomicAdd(&lh[v.y >> 8], 1);
        atomicAdd(&lh[v.z >> 8], 1);
        atomicAdd(&lh[v.w >> 8], 1);
    }
    __syncthreads();
    atomicAdd(&coarse[tid], lh[tid]);
}

// ---------------- partitioned src histogram: zero per-edge global atomics ----------------
// grid 128 = 8 partitions x 16 chunks; partial[c][n] streamed out
__global__ __launch_bounds__(256) void src_hist(const int4* __restrict__ src4,
                                                int* __restrict__ partial) {
    __shared__ int lbins[8192];   // 32 KB: 8192-node partition
    int tid = threadIdx.x;
    int p = blockIdx.x & 7;
    int c = blockIdx.x >> 3;
#pragma unroll
    for (int k = 0; k < 32; ++k) lbins[k * 256 + tid] = 0;
    __syncthreads();
    for (int k = 0; k < 64; ++k) {
        int4 v = src4[c * 16384 + k * 256 + tid];
        if ((v.x >> 13) == p) atomicAdd(&lbins[v.x & 8191], 1);
        if ((v.y >> 13) == p) atomicAdd(&lbins[v.y & 8191], 1);
        if ((v.z >> 13) == p) atomicAdd(&lbins[v.z & 8191], 1);
        if ((v.w >> 13) == p) atomicAdd(&lbins[v.w & 8191], 1);
    }
    __syncthreads();
    int* dstp = partial + c * 65536 + (p << 13);
#pragma unroll
    for (int k = 0; k < 32; ++k) dstp[k * 256 + tid] = lbins[k * 256 + tid];
}

__global__ __launch_bounds__(256) void reduce_src(const int* __restrict__ partial,
                                                  float* __restrict__ inv_so) {
    int n = blockIdx.x * 256 + threadIdx.x;
    int s = 0;
#pragma unroll
    for (int c = 0; c < 16; ++c) s += partial[c * 65536 + n];
    inv_so[n] = rsqrtf((float)max(s, 1));
}

// ---------------- scan coarse totals -> bucketBase + cursor init ----------------
__global__ __launch_bounds__(256) void scan_coarse(const int* __restrict__ coarse,
                                                   int* __restrict__ bucketBase,
                                                   int* __restrict__ cursor) {
    __shared__ int s[256];
    int tid = threadIdx.x;
    int my = coarse[tid];
    s[tid] = my;
    __syncthreads();
    for (int off = 1; off < 256; off <<= 1) {
        int t = (tid >= off) ? s[tid - off] : 0;
        __syncthreads();
        s[tid] += t;
        __syncthreads();
    }
    int excl = s[tid] - my;
    bucketBase[tid] = excl;
    cursor[tid] = excl;
    if (tid == 255) bucketBase[256] = s[255];
}

// ---------------- bucket scatter: LDS counting-sort per 4096-edge chunk ----------------
// payload int2: {src | dstlow<<16, w_bits}; flush = contiguous per-bucket runs
__global__ __launch_bounds__(256) void bucket_scatter(const int* __restrict__ src,
                                                      const int* __restrict__ dst,
                                                      const float* __restrict__ ew,
                                                      int* __restrict__ cursor,
                                                      int2* __restrict__ bedges) {
    __shared__ int lhist[NBUCKET];
    __shared__ int lstart[NBUCKET];
    __shared__ int gbase[NBUCKET];
    __shared__ int sc[NBUCKET];
    __shared__ int2 staged[4096];   // 32 KB
    int tid = threadIdx.x;
    int ebase = blockIdx.x * 4096;
    lhist[tid] = 0;
    __syncthreads();
    int w0[16]; int wbr[16]; float wwt[16];
#pragma unroll
    for (int k = 0; k < 16; ++k) {
        int e = ebase + k * 256 + tid;
        int s = src[e], d = dst[e];
        wwt[k] = ew[e];
        int b = d >> 8;
        w0[k] = s | ((d & 255) << 16);
        int r = atomicAdd(&lhist[b], 1);
        wbr[k] = (b << 16) | r;
    }
    __syncthreads();
    int cnt = lhist[tid];
    sc[tid] = cnt;
    __syncthreads();
    for (int off = 1; off < 256; off <<= 1) {
        int t = (tid >= off) ? sc[tid - off] : 0;
        __syncthreads();
        sc[tid] += t;
        __syncthreads();
    }
    lstart[tid] = sc[tid] - cnt;
    gbase[tid] = cnt ? atomicAdd(&cursor[tid], cnt) : 0;
    __syncthreads();
#pragma unroll
    for (int k = 0; k < 16; ++k)
        staged[lstart[wbr[k] >> 16] + (wbr[k] & 0xFFFF)] =
            make_int2(w0[k], __float_as_int(wwt[k]));
    __syncthreads();
    int gb = gbase[tid], ls = lstart[tid];
    for (int i = 0; i < cnt; ++i)
        bedges[gb + i] = staged[ls + i];
}

// ---------------- dense: out[r][c] = sum_k f(in[r][k]) * W[k][c] ----------------
__global__ __launch_bounds__(256) void gemm_kernel(const float* __restrict__ in,
                                                   const float* __restrict__ W,
                                                   const float* __restrict__ inv_so,
                                                   const float* __restrict__ alpha,
                                                   const float* __restrict__ beta,
                                                   float* __restrict__ out) {
    __shared__ float wT[64][68];    // wT[c][k] = W[k][c]; 68 keeps float4 alignment
    __shared__ float xlds[16][64];
    int tid = threadIdx.x;
#pragma unroll
    for (int j = 0; j < 16; ++j) {
        int i = j * 256 + tid;      // i = k*64 + c
        wT[i & 63][i >> 6] = W[i];
    }
    int r0 = blockIdx.x * 16;
#pragma unroll
    for (int j = 0; j < 4; ++j) {
        int i = j * 256 + tid;
        int r = i >> 6, k = i & 63;
        int gr = r0 + r;
        float v = in[(size_t)gr * 64 + k];
        if (alpha) v = alpha[k] * v + beta[k];
        xlds[r][k] = v * inv_so[gr];
    }
    __syncthreads();
    int c = tid & 63;
    int rg = tid >> 6;
    float acc[4] = {0.f, 0.f, 0.f, 0.f};
#pragma unroll
    for (int k0 = 0; k0 < 64; k0 += 4) {
        float4 wv = *(const float4*)&wT[c][k0];
#pragma unroll
        for (int j = 0; j < 4; ++j) {
            float4 xv = *(const float4*)&xlds[rg * 4 + j][k0];  // broadcast
            acc[j] += xv.x * wv.x + xv.y * wv.y + xv.z * wv.z + xv.w * wv.w;
        }
    }
#pragma unroll
    for (int j = 0; j < 4; ++j)
        out[(size_t)(r0 + rg * 4 + j) * 64 + c] = acc[j];
}

// ---------------- per-bucket LDS-accumulator aggregation ----------------
// block = bucket (256 nodes x 64 feats in LDS); full wave per edge, lane = feature
// fused: deg_in histogram, inv_si scale, LeakyReLU
__global__ __launch_bounds__(1024) void agg_lds(const float* __restrict__ T,
                                                const int2* __restrict__ bedges,
                                                const int* __restrict__ bucketBase,
                                                float* __restrict__ Y) {
    __shared__ float acc[NBUCKET * 64];   // 64 KB
    __shared__ int   hist[NBUCKET];
    __shared__ int2  est[1024];
    int tid = threadIdx.x;
    int b = blockIdx.x;
    float4* acc4 = (float4*)acc;
#pragma unroll
    for (int j = 0; j < 4; ++j)
        acc4[tid * 4 + j] = make_float4(0.f, 0.f, 0.f, 0.f);
    if (tid < NBUCKET) hist[tid] = 0;
    __syncthreads();
    int e0 = bucketBase[b], e1 = bucketBase[b + 1];
    int nE = e1 - e0;
    int wave = tid >> 6, lane = tid & 63;
    for (int base = 0; base < nE; base += 1024) {
        int idx = base + tid;
        if (idx < nE) est[tid] = bedges[e0 + idx];
        __syncthreads();
        int cnt = min(1024, nE - base);
        int lo = wave * 64;
        int hi = min(lo + 64, cnt);
#pragma unroll 4
        for (int i = lo; i < hi; ++i) {
            int2 e = est[i];                       // broadcast LDS read
            int s  = e.x & 0xFFFF;
            int dl = (e.x >> 16) & 0xFF;
            float wgt = __int_as_float(e.y);
            float v = T[(size_t)s * 64 + lane] * wgt;   // coalesced 256B gather
            __hip_atomic_fetch_add(&acc[dl * 64 + lane], v,
                                   __ATOMIC_RELAXED, __HIP_MEMORY_SCOPE_WORKGROUP);
            if (lane == 0) atomicAdd(&hist[dl], 1);
        }
        __syncthreads();
    }
    // epilogue: inv_si scale + LeakyReLU, coalesced store
    int n = tid >> 2, q = tid & 3;
    float isq = rsqrtf((float)max(hist[n], 1));
    float4* Y4 = (float4*)(Y + (size_t)b * NBUCKET * 64);
#pragma unroll
    for (int j = 0; j < 4; ++j) {
        float4 a = acc4[n * 16 + q * 4 + j];
        float4 v;
        v.x = a.x * isq; v.x = (v.x >= 0.f) ? v.x : SLOPE * v.x;
        v.y = a.y * isq; v.y = (v.y >= 0.f) ? v.y : SLOPE * v.y;
        v.z = a.z * isq; v.z = (v.z >= 0.f) ? v.z : SLOPE * v.z;
        v.w = a.w * isq; v.w = (v.w >= 0.f) ? v.w : SLOPE * v.w;
        Y4[n * 16 + q * 4 + j] = v;
    }
}

// ---------------- per-feature sums for GraphNorm ----------------
__global__ __launch_bounds__(256) void stats_kernel(const float* __restrict__ y,
                                                    float* __restrict__ Sy,
                                                    float* __restrict__ Syy) {
    __shared__ float ls[4][64];
    __shared__ float lq[4][64];
    int tid = threadIdx.x;
    int lane = tid & 63, wave = tid >> 6;
    float s = 0.f, q = 0.f;
    int base = blockIdx.x * 256 + wave * 64;
    for (int i = 0; i < 64; ++i) {
        float v = y[(size_t)(base + i) * 64 + lane];
        s += v;
        q += v * v;
    }
    ls[wave][lane] = s;
    lq[wave][lane] = q;
    __syncthreads();
    if (wave == 0) {
        float ts = ls[0][lane] + ls[1][lane] + ls[2][lane] + ls[3][lane];
        float tq = lq[0][lane] + lq[1][lane] + lq[2][lane] + lq[3][lane];
        atomicAdd(&Sy[lane], ts);
        atomicAdd(&Syy[lane], tq);
    }
}

// GraphNorm(y) = alpha*y + beta, with var = E[y^2] - 2a m E[y] + a^2 m^2
__global__ void finalize_kernel(const float* __restrict__ Sy, const float* __restrict__ Syy,
                                const float* __restrict__ w, const float* __restrict__ b,
                                const float* __restrict__ a,
                                float* __restrict__ alpha, float* __restrict__ beta) {
    int f = threadIdx.x;
    if (f < 64) {
        float m = Sy[f] * (1.f / N_NODES);
        float q = Syy[f] * (1.f / N_NODES);
        float af = a[f];
        float var = q - 2.f * af * m * m + af * af * m * m;
        float stdv = sqrtf(var + EPS_GN);
        float al = w[f] / stdv;
        alpha[f] = al;
        beta[f] = b[f] - al * af * m;
    }
}

// ---------------- per-graph mean pool + GN affine ----------------
__global__ __launch_bounds__(256) void pool_kernel(const float* __restrict__ y,
                                                   const float* __restrict__ alpha,
                                                   const float* __restrict__ beta,
                                                   float* __restrict__ pooled) {
    __shared__ float ls[4][64];
    int tid = threadIdx.x;
    int lane = tid & 63, wave = tid >> 6;
    int g = blockIdx.x;
    float s = 0.f;
    int base = g * NPG + wave * 512;
    for (int i = 0; i < 512; ++i)
        s += y[(size_t)(base + i) * 64 + lane];
    ls[wave][lane] = s;
    __syncthreads();
    if (wave == 0) {
        float tot = ls[0][lane] + ls[1][lane] + ls[2][lane] + ls[3][lane];
        pooled[g * 64 + lane] = alpha[lane] * (tot * (1.f / NPG)) + beta[lane];
    }
}

__global__ __launch_bounds__(256) void out_kernel(const float* __restrict__ pooled,
                                                  const float* __restrict__ Wc,
                                                  float* __restrict__ out) {
    int tid = threadIdx.x;
    for (int idx = tid; idx < B_GRAPHS * 32; idx += 256) {
        int g = idx >> 5, o = idx & 31;
        float acc = 0.f;
        for (int f = 0; f < 64; ++f)
            acc += pooled[g * 64 + f] * Wc[o * 64 + f];
        out[idx] = acc;
    }
}

extern "C" void kernel_launch(void* const* d_in, const int* in_sizes, int n_in,
                              void* d_out, int out_size, void* d_ws, size_t ws_size,
                              hipStream_t stream) {
    const float* x     = (const float*)d_in[0];
    const float* ew    = (const float*)d_in[1];
    const float* W1    = (const float*)d_in[2];
    const float* W2    = (const float*)d_in[3];
    const float* Wc    = (const float*)d_in[4];
    const float* gn1_w = (const float*)d_in[5];
    const float* gn1_b = (const float*)d_in[6];
    const float* gn1_a = (const float*)d_in[7];
    const float* gn2_w = (const float*)d_in[8];
    const float* gn2_b = (const float*)d_in[9];
    const float* gn2_a = (const float*)d_in[10];
    const int* src     = (const int*)d_in[11];
    const int* dst     = (const int*)d_in[12];

    char* ws = (char*)d_ws;
    int*   coarse     = (int*)(ws + 0);            // 1 KB (memset)
    float* stats      = (float*)(ws + 1024);       // 1 KB (memset)
    float* ab         = (float*)(ws + 2048);       // 1 KB
    int*   bucketBase = (int*)(ws + 3072);         // 257 ints
    int*   cursor     = (int*)(ws + 5120);         // 1 KB
    float* inv_so     = (float*)(ws + (1u << 20)); // 256 KB
    int*   partial    = (int*)(ws + (2u << 20));   // 4 MB (16 x 65536)
    int2*  bedges     = (int2*)(ws + (6u << 20));  // 8 MB
    float* bufA       = (float*)(ws + (14u << 20)); // 16 MB
    float* bufB       = (float*)(ws + (30u << 20)); // 16 MB
    float* pooled     = (float*)(ws + (46u << 20)); // 8 KB

    hipMemsetAsync(ws, 0, 2048, stream);

    // graph structure (recomputed each call)
    coarse_hist<<<64, 256, 0, stream>>>((const int4*)dst, coarse);
    src_hist<<<128, 256, 0, stream>>>((const int4*)src, partial);
    scan_coarse<<<1, 256, 0, stream>>>(coarse, bucketBase, cursor);
    reduce_src<<<256, 256, 0, stream>>>(partial, inv_so);
    bucket_scatter<<<256, 256, 0, stream>>>(src, dst, ew, cursor, bedges);

    // layer 1
    gemm_kernel<<<N_NODES / 16, 256, 0, stream>>>(x, W1, inv_so, nullptr, nullptr, bufA);
    agg_lds<<<NBUCKET, 1024, 0, stream>>>(bufA, bedges, bucketBase, bufB);
    stats_kernel<<<256, 256, 0, stream>>>(bufB, stats + 0, stats + 64);
    finalize_kernel<<<1, 64, 0, stream>>>(stats + 0, stats + 64, gn1_w, gn1_b, gn1_a,
                                          ab + 0, ab + 64);

    // layer 2 (GraphNorm-1 affine fused into GEMM2 load)
    gemm_kernel<<<N_NODES / 16, 256, 0, stream>>>(bufB, W2, inv_so, ab + 0, ab + 64, bufA);
    agg_lds<<<NBUCKET, 1024, 0, stream>>>(bufA, bedges, bucketBase, bufB);
    stats_kernel<<<256, 256, 0, stream>>>(bufB, stats + 128, stats + 192);
    finalize_kernel<<<1, 64, 0, stream>>>(stats + 128, stats + 192, gn2_w, gn2_b, gn2_a,
                                          ab + 128, ab + 192);

    // pool (GraphNorm-2 affine fused) + classifier
    pool_kernel<<<B_GRAPHS, 256, 0, stream>>>(bufB, ab + 128, ab + 192, pooled);
    out_kernel<<<1, 256, 0, stream>>>(pooled, Wc, (float*)d_out);
}

// Round 4
// 262.913 us; speedup vs baseline: 3.4704x; 3.4704x over previous
//
#include <hip/hip_runtime.h>

#define N_NODES 65536
#define N_EDGES 1048576
#define B_GRAPHS 32
#define NPG     2048
#define EPS_GN  1e-5f
#define SLOPE   0.01f
#define NBUCKET 256    // coarse buckets (dst>>8), 256 nodes each
#define STCAP   5120   // refine LDS staging capacity (mean 4096 + >10 sigma)

// ---------------- coarse dst-bucket histogram (LDS-privatized) ----------------
__global__ __launch_bounds__(256) void coarse_hist(const int4* __restrict__ dst4,
                                                   int* __restrict__ coarse) {
    __shared__ int lh[256];
    int tid = threadIdx.x;
    lh[tid] = 0;
    __syncthreads();
#pragma unroll
    for (int k = 0; k < 16; ++k) {
        int4 v = dst4[blockIdx.x * 4096 + k * 256 + tid];
        atomicAdd(&lh[v.x >> 8], 1);
        atomicAdd(&lh[v.y >> 8], 1);
        atomicAdd(&lh[v.z >> 8], 1);
        atomicAdd(&lh[v.w >> 8], 1);
    }
    __syncthreads();
    atomicAdd(&coarse[tid], lh[tid]);
}

// ---------------- partitioned src histogram: zero per-edge global atomics ----------------
__global__ __launch_bounds__(256) void src_hist(const int4* __restrict__ src4,
                                                int* __restrict__ partial) {
    __shared__ int lbins[8192];   // 32 KB: 8192-node partition
    int tid = threadIdx.x;
    int p = blockIdx.x & 7;
    int c = blockIdx.x >> 3;
#pragma unroll
    for (int k = 0; k < 32; ++k) lbins[k * 256 + tid] = 0;
    __syncthreads();
    for (int k = 0; k < 64; ++k) {
        int4 v = src4[c * 16384 + k * 256 + tid];
        if ((v.x >> 13) == p) atomicAdd(&lbins[v.x & 8191], 1);
        if ((v.y >> 13) == p) atomicAdd(&lbins[v.y & 8191], 1);
        if ((v.z >> 13) == p) atomicAdd(&lbins[v.z & 8191], 1);
        if ((v.w >> 13) == p) atomicAdd(&lbins[v.w & 8191], 1);
    }
    __syncthreads();
    int* dstp = partial + c * 65536 + (p << 13);
#pragma unroll
    for (int k = 0; k < 32; ++k) dstp[k * 256 + tid] = lbins[k * 256 + tid];
}

__global__ __launch_bounds__(256) void reduce_src(const int* __restrict__ partial,
                                                  float* __restrict__ inv_so) {
    int n = blockIdx.x * 256 + threadIdx.x;
    int s = 0;
#pragma unroll
    for (int c = 0; c < 16; ++c) s += partial[c * 65536 + n];
    inv_so[n] = rsqrtf((float)max(s, 1));
}

// ---------------- scan coarse totals -> bucketBase + cursor init ----------------
__global__ __launch_bounds__(256) void scan_coarse(const int* __restrict__ coarse,
                                                   int* __restrict__ bucketBase,
                                                   int* __restrict__ cursor) {
    __shared__ int s[256];
    int tid = threadIdx.x;
    int my = coarse[tid];
    s[tid] = my;
    __syncthreads();
    for (int off = 1; off < 256; off <<= 1) {
        int t = (tid >= off) ? s[tid - off] : 0;
        __syncthreads();
        s[tid] += t;
        __syncthreads();
    }
    int excl = s[tid] - my;
    bucketBase[tid] = excl;
    cursor[tid] = excl;
    if (tid == 255) bucketBase[256] = s[255];
}

// ---------------- bucket scatter: LDS counting-sort per 4096-edge chunk ----------------
// payload int2: {src | dstlow<<16, w_bits}; flush = contiguous per-bucket runs
__global__ __launch_bounds__(256) void bucket_scatter(const int* __restrict__ src,
                                                      const int* __restrict__ dst,
                                                      const float* __restrict__ ew,
                                                      int* __restrict__ cursor,
                                                      int2* __restrict__ bedges) {
    __shared__ int lhist[NBUCKET];
    __shared__ int lstart[NBUCKET];
    __shared__ int gbase[NBUCKET];
    __shared__ int sc[NBUCKET];
    __shared__ int2 staged[4096];   // 32 KB
    int tid = threadIdx.x;
    int ebase = blockIdx.x * 4096;
    lhist[tid] = 0;
    __syncthreads();
    int w0[16]; int wbr[16]; float wwt[16];
#pragma unroll
    for (int k = 0; k < 16; ++k) {
        int e = ebase + k * 256 + tid;
        int s = src[e], d = dst[e];
        wwt[k] = ew[e];
        int b = d >> 8;
        w0[k] = s | ((d & 255) << 16);
        int r = atomicAdd(&lhist[b], 1);
        wbr[k] = (b << 16) | r;
    }
    __syncthreads();
    int cnt = lhist[tid];
    sc[tid] = cnt;
    __syncthreads();
    for (int off = 1; off < 256; off <<= 1) {
        int t = (tid >= off) ? sc[tid - off] : 0;
        __syncthreads();
        sc[tid] += t;
        __syncthreads();
    }
    lstart[tid] = sc[tid] - cnt;
    gbase[tid] = cnt ? atomicAdd(&cursor[tid], cnt) : 0;
    __syncthreads();
#pragma unroll
    for (int k = 0; k < 16; ++k)
        staged[lstart[wbr[k] >> 16] + (wbr[k] & 0xFFFF)] =
            make_int2(w0[k], __float_as_int(wwt[k]));
    __syncthreads();
    int gb = gbase[tid], ls = lstart[tid];
    for (int i = 0; i < cnt; ++i)
        bedges[gb + i] = staged[ls + i];
}

// ---------------- refine: bucket-sorted -> full per-node CSR + rowp + inv_si ----------------
// one block per bucket; LDS counting sort over the bucket's 256 nodes
__global__ __launch_bounds__(256) void refine_kernel(const int2* __restrict__ bedges,
                                                     const int* __restrict__ bucketBase,
                                                     int* __restrict__ rowp,
                                                     float* __restrict__ inv_si,
                                                     int2* __restrict__ csr) {
    __shared__ int hist[256], sc[256], cur[256];
    __shared__ int2 staged[STCAP];   // 40 KB
    int tid = threadIdx.x, b = blockIdx.x;
    int e0 = bucketBase[b], e1 = bucketBase[b + 1];
    int nE = e1 - e0;
    hist[tid] = 0;
    __syncthreads();
    for (int i = tid; i < nE; i += 256) {
        int2 e = bedges[e0 + i];
        if (i < STCAP) staged[i] = e;
        atomicAdd(&hist[(e.x >> 16) & 255], 1);
    }
    __syncthreads();
    int cnt = hist[tid];
    sc[tid] = cnt;
    __syncthreads();
    for (int off = 1; off < 256; off <<= 1) {
        int t = (tid >= off) ? sc[tid - off] : 0;
        __syncthreads();
        sc[tid] += t;
        __syncthreads();
    }
    int excl = sc[tid] - cnt;
    cur[tid] = excl;
    rowp[b * 256 + tid] = e0 + excl;
    inv_si[b * 256 + tid] = rsqrtf((float)max(cnt, 1));
    if (b == 255 && tid == 255) rowp[65536] = N_EDGES;
    __syncthreads();
    for (int i = tid; i < nE; i += 256) {
        int2 e = (i < STCAP) ? staged[i] : bedges[e0 + i];
        int dl = (e.x >> 16) & 255;
        int pos = atomicAdd(&cur[dl], 1);
        csr[e0 + pos] = make_int2(e.x & 0xFFFF, e.y);   // src fits 16 bits (N=65536)
    }
}

// ---------------- dense: out[r][c] = sum_k f(in[r][k]) * W[k][c] ----------------
__global__ __launch_bounds__(256) void gemm_kernel(const float* __restrict__ in,
                                                   const float* __restrict__ W,
                                                   const float* __restrict__ inv_so,
                                                   const float* __restrict__ alpha,
                                                   const float* __restrict__ beta,
                                                   float* __restrict__ out) {
    __shared__ float wT[64][68];
    __shared__ float xlds[16][64];
    int tid = threadIdx.x;
#pragma unroll
    for (int j = 0; j < 16; ++j) {
        int i = j * 256 + tid;
        wT[i & 63][i >> 6] = W[i];
    }
    int r0 = blockIdx.x * 16;
#pragma unroll
    for (int j = 0; j < 4; ++j) {
        int i = j * 256 + tid;
        int r = i >> 6, k = i & 63;
        int gr = r0 + r;
        float v = in[(size_t)gr * 64 + k];
        if (alpha) v = alpha[k] * v + beta[k];
        xlds[r][k] = v * inv_so[gr];
    }
    __syncthreads();
    int c = tid & 63;
    int rg = tid >> 6;
    float acc[4] = {0.f, 0.f, 0.f, 0.f};
#pragma unroll
    for (int k0 = 0; k0 < 64; k0 += 4) {
        float4 wv = *(const float4*)&wT[c][k0];
#pragma unroll
        for (int j = 0; j < 4; ++j) {
            float4 xv = *(const float4*)&xlds[rg * 4 + j][k0];
            acc[j] += xv.x * wv.x + xv.y * wv.y + xv.z * wv.z + xv.w * wv.w;
        }
    }
#pragma unroll
    for (int j = 0; j < 4; ++j)
        out[(size_t)(r0 + rg * 4 + j) * 64 + c] = acc[j];
}

// ---------------- pull-aggregation + inv_si scale + LeakyReLU ----------------
// 16 lanes/node, float4/lane; unroll 8 -> ~32 outstanding gathers per wave
__global__ __launch_bounds__(256) void agg_kernel(const float4* __restrict__ T4,
                                                  const int* __restrict__ rowp,
                                                  const float* __restrict__ inv_si,
                                                  const int2* __restrict__ csr,
                                                  float4* __restrict__ Y4) {
    int tid = threadIdx.x;
    int node = blockIdx.x * 16 + (tid >> 4);
    int l16 = tid & 15;
    int start = rowp[node];
    int cnt = rowp[node + 1] - start;
    const int2* ep = csr + start;
    float4 acc = make_float4(0.f, 0.f, 0.f, 0.f);
    int i = 0;
    for (; i + 8 <= cnt; i += 8) {
        int2 e[8];
#pragma unroll
        for (int k = 0; k < 8; ++k) e[k] = ep[i + k];
        float4 a[8];
#pragma unroll
        for (int k = 0; k < 8; ++k) a[k] = T4[(size_t)e[k].x * 16 + l16];
#pragma unroll
        for (int k = 0; k < 8; ++k) {
            float w = __int_as_float(e[k].y);
            acc.x += a[k].x * w;
            acc.y += a[k].y * w;
            acc.z += a[k].z * w;
            acc.w += a[k].w * w;
        }
    }
    for (; i + 2 <= cnt; i += 2) {
        int2 e0 = ep[i], e1 = ep[i + 1];
        float4 a0 = T4[(size_t)e0.x * 16 + l16];
        float4 a1 = T4[(size_t)e1.x * 16 + l16];
        float w0 = __int_as_float(e0.y), w1 = __int_as_float(e1.y);
        acc.x += a0.x * w0 + a1.x * w1;
        acc.y += a0.y * w0 + a1.y * w1;
        acc.z += a0.z * w0 + a1.z * w1;
        acc.w += a0.w * w0 + a1.w * w1;
    }
    if (i < cnt) {
        int2 e = ep[i];
        float4 a = T4[(size_t)e.x * 16 + l16];
        float w = __int_as_float(e.y);
        acc.x += a.x * w; acc.y += a.y * w; acc.z += a.z * w; acc.w += a.w * w;
    }
    float s = inv_si[node];
    float4 v;
    v.x = acc.x * s; v.x = (v.x >= 0.f) ? v.x : SLOPE * v.x;
    v.y = acc.y * s; v.y = (v.y >= 0.f) ? v.y : SLOPE * v.y;
    v.z = acc.z * s; v.z = (v.z >= 0.f) ? v.z : SLOPE * v.z;
    v.w = acc.w * s; v.w = (v.w >= 0.f) ? v.w : SLOPE * v.w;
    Y4[(size_t)node * 16 + l16] = v;
}

// ---------------- per-feature sums for GraphNorm (float4) ----------------
__global__ __launch_bounds__(256) void stats_kernel(const float4* __restrict__ Y4,
                                                    float* __restrict__ Sy,
                                                    float* __restrict__ Syy) {
    __shared__ float4 ls[256];
    __shared__ float4 lq[256];
    int tid = threadIdx.x;
    int l16 = tid & 15, g = tid >> 4;
    float4 s = make_float4(0.f, 0.f, 0.f, 0.f);
    float4 q = make_float4(0.f, 0.f, 0.f, 0.f);
    size_t base = (size_t)blockIdx.x * 256 + g * 16;
    for (int r = 0; r < 16; ++r) {
        float4 v = Y4[(base + r) * 16 + l16];
        s.x += v.x; s.y += v.y; s.z += v.z; s.w += v.w;
        q.x += v.x * v.x; q.y += v.y * v.y; q.z += v.z * v.z; q.w += v.w * v.w;
    }
    ls[tid] = s; lq[tid] = q;
    __syncthreads();
    for (int off = 128; off >= 16; off >>= 1) {
        if (tid < off) {
            float4 a = ls[tid + off], b = lq[tid + off];
            ls[tid].x += a.x; ls[tid].y += a.y; ls[tid].z += a.z; ls[tid].w += a.w;
            lq[tid].x += b.x; lq[tid].y += b.y; lq[tid].z += b.z; lq[tid].w += b.w;
        }
        __syncthreads();
    }
    if (tid < 16) {
        float4 a = ls[tid], b = lq[tid];
        atomicAdd(&Sy[tid * 4 + 0], a.x); atomicAdd(&Sy[tid * 4 + 1], a.y);
        atomicAdd(&Sy[tid * 4 + 2], a.z); atomicAdd(&Sy[tid * 4 + 3], a.w);
        atomicAdd(&Syy[tid * 4 + 0], b.x); atomicAdd(&Syy[tid * 4 + 1], b.y);
        atomicAdd(&Syy[tid * 4 + 2], b.z); atomicAdd(&Syy[tid * 4 + 3], b.w);
    }
}

// GraphNorm(y) = alpha*y + beta
__global__ void finalize_kernel(const float* __restrict__ Sy, const float* __restrict__ Syy,
                                const float* __restrict__ w, const float* __restrict__ b,
                                const float* __restrict__ a,
                                float* __restrict__ alpha, float* __restrict__ beta) {
    int f = threadIdx.x;
    if (f < 64) {
        float m = Sy[f] * (1.f / N_NODES);
        float q = Syy[f] * (1.f / N_NODES);
        float af = a[f];
        float var = q - 2.f * af * m * m + af * af * m * m;
        float stdv = sqrtf(var + EPS_GN);
        float al = w[f] / stdv;
        alpha[f] = al;
        beta[f] = b[f] - al * af * m;
    }
}

// ---------------- pool partials: 256 nodes/block -> atomicAdd per-graph sums ----------------
__global__ __launch_bounds__(256) void pool_kernel(const float4* __restrict__ Y4,
                                                   float* __restrict__ pooledSum) {
    __shared__ float4 ls[256];
    int tid = threadIdx.x;
    int l16 = tid & 15, g = tid >> 4;
    size_t base = (size_t)blockIdx.x * 256 + g * 16;
    float4 s = make_float4(0.f, 0.f, 0.f, 0.f);
    for (int r = 0; r < 16; ++r) {
        float4 v = Y4[(base + r) * 16 + l16];
        s.x += v.x; s.y += v.y; s.z += v.z; s.w += v.w;
    }
    ls[tid] = s;
    __syncthreads();
    for (int off = 128; off >= 16; off >>= 1) {
        if (tid < off) {
            float4 a = ls[tid + off];
            ls[tid].x += a.x; ls[tid].y += a.y; ls[tid].z += a.z; ls[tid].w += a.w;
        }
        __syncthreads();
    }
    int graph = blockIdx.x >> 3;   // 8 blocks per graph (2048 nodes)
    if (tid < 16) {
        float4 a = ls[tid];
        atomicAdd(&pooledSum[graph * 64 + tid * 4 + 0], a.x);
        atomicAdd(&pooledSum[graph * 64 + tid * 4 + 1], a.y);
        atomicAdd(&pooledSum[graph * 64 + tid * 4 + 2], a.z);
        atomicAdd(&pooledSum[graph * 64 + tid * 4 + 3], a.w);
    }
}

// ---------------- final: GN2 affine on pooled mean, then @ Wc^T ----------------
__global__ __launch_bounds__(256) void out_kernel(const float* __restrict__ pooledSum,
                                                  const float* __restrict__ alpha,
                                                  const float* __restrict__ beta,
                                                  const float* __restrict__ Wc,
                                                  float* __restrict__ out) {
    __shared__ float p[B_GRAPHS * 64];
    int tid = threadIdx.x;
    for (int i = tid; i < B_GRAPHS * 64; i += 256) {
        int f = i & 63;
        p[i] = alpha[f] * (pooledSum[i] * (1.f / NPG)) + beta[f];
    }
    __syncthreads();
    for (int idx = tid; idx < B_GRAPHS * 32; idx += 256) {
        int g = idx >> 5, o = idx & 31;
        float acc = 0.f;
        for (int f = 0; f < 64; ++f)
            acc += p[g * 64 + f] * Wc[o * 64 + f];
        out[idx] = acc;
    }
}

extern "C" void kernel_launch(void* const* d_in, const int* in_sizes, int n_in,
                              void* d_out, int out_size, void* d_ws, size_t ws_size,
                              hipStream_t stream) {
    const float* x     = (const float*)d_in[0];
    const float* ew    = (const float*)d_in[1];
    const float* W1    = (const float*)d_in[2];
    const float* W2    = (const float*)d_in[3];
    const float* Wc    = (const float*)d_in[4];
    const float* gn1_w = (const float*)d_in[5];
    const float* gn1_b = (const float*)d_in[6];
    const float* gn1_a = (const float*)d_in[7];
    const float* gn2_w = (const float*)d_in[8];
    const float* gn2_b = (const float*)d_in[9];
    const float* gn2_a = (const float*)d_in[10];
    const int* src     = (const int*)d_in[11];
    const int* dst     = (const int*)d_in[12];

    char* ws = (char*)d_ws;
    int*   coarse     = (int*)(ws + 0);             // 1 KB   [memset]
    float* stats      = (float*)(ws + 1024);        // 1 KB   [memset]
    float* pooledSum  = (float*)(ws + 2048);        // 8 KB   [memset]
    float* ab         = (float*)(ws + 10240);       // 1 KB
    int*   bucketBase = (int*)(ws + 11264);         // 257 ints
    int*   cursor     = (int*)(ws + 12544);         // 1 KB
    int*   rowp       = (int*)(ws + 16384);         // 65537 ints
    float* inv_so     = (float*)(ws + 294912);      // 256 KB
    float* inv_si     = (float*)(ws + 557056);      // 256 KB
    int*   partial    = (int*)(ws + (1u << 20));    // 4 MB (dead after reduce_src)
    int2*  csr        = (int2*)(ws + (1u << 20));   // 8 MB (overlaps partial)
    int2*  bedges     = (int2*)(ws + (9u << 20));   // 8 MB
    float* bufA       = (float*)(ws + (17u << 20)); // 16 MB
    float* bufB       = (float*)(ws + (33u << 20)); // 16 MB

    hipMemsetAsync(ws, 0, 10240, stream);

    // graph structure (recomputed each call)
    coarse_hist<<<64, 256, 0, stream>>>((const int4*)dst, coarse);
    src_hist<<<128, 256, 0, stream>>>((const int4*)src, partial);
    scan_coarse<<<1, 256, 0, stream>>>(coarse, bucketBase, cursor);
    reduce_src<<<256, 256, 0, stream>>>(partial, inv_so);
    bucket_scatter<<<256, 256, 0, stream>>>(src, dst, ew, cursor, bedges);
    refine_kernel<<<NBUCKET, 256, 0, stream>>>(bedges, bucketBase, rowp, inv_si, csr);

    // layer 1
    gemm_kernel<<<N_NODES / 16, 256, 0, stream>>>(x, W1, inv_so, nullptr, nullptr, bufA);
    agg_kernel<<<N_NODES / 16, 256, 0, stream>>>((const float4*)bufA, rowp, inv_si, csr,
                                                 (float4*)bufB);
    stats_kernel<<<256, 256, 0, stream>>>((const float4*)bufB, stats + 0, stats + 64);
    finalize_kernel<<<1, 64, 0, stream>>>(stats + 0, stats + 64, gn1_w, gn1_b, gn1_a,
                                          ab + 0, ab + 64);

    // layer 2 (GraphNorm-1 affine fused into GEMM2 load)
    gemm_kernel<<<N_NODES / 16, 256, 0, stream>>>(bufB, W2, inv_so, ab + 0, ab + 64, bufA);
    agg_kernel<<<N_NODES / 16, 256, 0, stream>>>((const float4*)bufA, rowp, inv_si, csr,
                                                 (float4*)bufB);
    stats_kernel<<<256, 256, 0, stream>>>((const float4*)bufB, stats + 128, stats + 192);
    finalize_kernel<<<1, 64, 0, stream>>>(stats + 128, stats + 192, gn2_w, gn2_b, gn2_a,
                                          ab + 128, ab + 192);

    // pool (per-graph sums) + classifier (GraphNorm-2 affine fused)
    pool_kernel<<<N_NODES / 256, 256, 0, stream>>>((const float4*)bufB, pooledSum);
    out_kernel<<<1, 256, 0, stream>>>(pooledSum, ab + 128, ab + 192, Wc, (float*)d_out);
}

// Round 5
// 230.487 us; speedup vs baseline: 3.9586x; 1.1407x over previous
//
#include <hip/hip_runtime.h>

#define N_NODES 65536
#define N_EDGES 1048576
#define B_GRAPHS 32
#define NPG     2048
#define EPS_GN  1e-5f
#define SLOPE   0.01f
#define NBUCKET 256    // coarse buckets (dst>>8), 256 nodes each
#define STCAP   5120   // refine LDS staging capacity (mean 4096 + >10 sigma)

// ---------------- coarse dst-bucket histogram (LDS-privatized) ----------------
__global__ __launch_bounds__(256) void coarse_hist(const int4* __restrict__ dst4,
                                                   int* __restrict__ coarse) {
    __shared__ int lh[256];
    int tid = threadIdx.x;
    lh[tid] = 0;
    __syncthreads();
#pragma unroll
    for (int k = 0; k < 16; ++k) {
        int4 v = dst4[blockIdx.x * 4096 + k * 256 + tid];
        atomicAdd(&lh[v.x >> 8], 1);
        atomicAdd(&lh[v.y >> 8], 1);
        atomicAdd(&lh[v.z >> 8], 1);
        atomicAdd(&lh[v.w >> 8], 1);
    }
    __syncthreads();
    atomicAdd(&coarse[tid], lh[tid]);
}

// ---------------- src histogram: single pass, byte-packed LDS bins ----------------
// 64 chunks x 16384 edges; 64K nodes as 16384 words x 4 byte-counters
__global__ __launch_bounds__(256) void src_hist(const int4* __restrict__ src4,
                                                unsigned int* __restrict__ partial) {
    __shared__ unsigned int bins[16384];   // 64 KB
    int tid = threadIdx.x, c = blockIdx.x;
#pragma unroll
    for (int k = 0; k < 64; ++k) bins[k * 256 + tid] = 0u;
    __syncthreads();
#pragma unroll
    for (int k = 0; k < 16; ++k) {
        int4 v = src4[c * 4096 + k * 256 + tid];
        atomicAdd(&bins[v.x >> 2], 1u << ((v.x & 3) * 8));
        atomicAdd(&bins[v.y >> 2], 1u << ((v.y & 3) * 8));
        atomicAdd(&bins[v.z >> 2], 1u << ((v.z & 3) * 8));
        atomicAdd(&bins[v.w >> 2], 1u << ((v.w & 3) * 8));
    }
    __syncthreads();
    unsigned int* dstp = partial + c * 16384;
#pragma unroll
    for (int k = 0; k < 64; ++k) dstp[k * 256 + tid] = bins[k * 256 + tid];
}

// sum byte-counters across 64 chunks -> inv_so (float4 store, 4 nodes/thread)
__global__ __launch_bounds__(256) void reduce_src(const unsigned int* __restrict__ partial,
                                                  float4* __restrict__ inv_so4) {
    int w = blockIdx.x * 256 + threadIdx.x;   // word idx, grid 64
    unsigned int s0 = 0, s1 = 0, s2 = 0, s3 = 0;
#pragma unroll
    for (int c = 0; c < 64; ++c) {
        unsigned int v = partial[c * 16384 + w];
        s0 += v & 255u; s1 += (v >> 8) & 255u; s2 += (v >> 16) & 255u; s3 += v >> 24;
    }
    float4 r;
    r.x = rsqrtf((float)max((int)s0, 1));
    r.y = rsqrtf((float)max((int)s1, 1));
    r.z = rsqrtf((float)max((int)s2, 1));
    r.w = rsqrtf((float)max((int)s3, 1));
    inv_so4[w] = r;
}

// ---------------- scan coarse totals -> bucketBase + cursor init ----------------
__global__ __launch_bounds__(256) void scan_coarse(const int* __restrict__ coarse,
                                                   int* __restrict__ bucketBase,
                                                   int* __restrict__ cursor) {
    __shared__ int s[256];
    int tid = threadIdx.x;
    int my = coarse[tid];
    s[tid] = my;
    __syncthreads();
    for (int off = 1; off < 256; off <<= 1) {
        int t = (tid >= off) ? s[tid - off] : 0;
        __syncthreads();
        s[tid] += t;
        __syncthreads();
    }
    int excl = s[tid] - my;
    bucketBase[tid] = excl;
    cursor[tid] = excl;
    if (tid == 255) bucketBase[256] = s[255];
}

// ---------------- bucket scatter: LDS counting-sort per 4096-edge chunk ----------------
__global__ __launch_bounds__(256) void bucket_scatter(const int4* __restrict__ src4,
                                                      const int4* __restrict__ dst4,
                                                      const float4* __restrict__ ew4,
                                                      int* __restrict__ cursor,
                                                      int2* __restrict__ bedges) {
    __shared__ int lhist[NBUCKET];
    __shared__ int lstart[NBUCKET];
    __shared__ int gbase[NBUCKET];
    __shared__ int sc[NBUCKET];
    __shared__ int2 staged[4096];   // 32 KB
    int tid = threadIdx.x;
    int vbase = blockIdx.x * 1024;  // int4 index base (4096 edges)
    lhist[tid] = 0;
    __syncthreads();
    int w0[16]; int wbr[16]; float wwt[16];
#pragma unroll
    for (int k = 0; k < 4; ++k) {
        int4 s = src4[vbase + k * 256 + tid];
        int4 d = dst4[vbase + k * 256 + tid];
        float4 w = ew4[vbase + k * 256 + tid];
        int ss[4] = {s.x, s.y, s.z, s.w};
        int dd[4] = {d.x, d.y, d.z, d.w};
        float wf[4] = {w.x, w.y, w.z, w.w};
#pragma unroll
        for (int j = 0; j < 4; ++j) {
            int b = dd[j] >> 8;
            w0[k * 4 + j] = ss[j] | ((dd[j] & 255) << 16);
            wwt[k * 4 + j] = wf[j];
            int r = atomicAdd(&lhist[b], 1);
            wbr[k * 4 + j] = (b << 16) | r;
        }
    }
    __syncthreads();
    int cnt = lhist[tid];
    sc[tid] = cnt;
    __syncthreads();
    for (int off = 1; off < 256; off <<= 1) {
        int t = (tid >= off) ? sc[tid - off] : 0;
        __syncthreads();
        sc[tid] += t;
        __syncthreads();
    }
    lstart[tid] = sc[tid] - cnt;
    gbase[tid] = cnt ? atomicAdd(&cursor[tid], cnt) : 0;
    __syncthreads();
#pragma unroll
    for (int k = 0; k < 16; ++k)
        staged[lstart[wbr[k] >> 16] + (wbr[k] & 0xFFFF)] =
            make_int2(w0[k], __float_as_int(wwt[k]));
    __syncthreads();
    int gb = gbase[tid], ls = lstart[tid];
    for (int i = 0; i < cnt; ++i)
        bedges[gb + i] = staged[ls + i];
}

// ---------------- refine: bucket-sorted -> full per-node CSR + rowp + inv_si ----------------
__global__ __launch_bounds__(256) void refine_kernel(const int2* __restrict__ bedges,
                                                     const int* __restrict__ bucketBase,
                                                     int* __restrict__ rowp,
                                                     float* __restrict__ inv_si,
                                                     int2* __restrict__ csr) {
    __shared__ int hist[256], sc[256], cur[256];
    __shared__ int2 staged[STCAP];   // 40 KB
    int tid = threadIdx.x, b = blockIdx.x;
    int e0 = bucketBase[b], e1 = bucketBase[b + 1];
    int nE = e1 - e0;
    hist[tid] = 0;
    __syncthreads();
    for (int i = tid; i < nE; i += 256) {
        int2 e = bedges[e0 + i];
        if (i < STCAP) staged[i] = e;
        atomicAdd(&hist[(e.x >> 16) & 255], 1);
    }
    __syncthreads();
    int cnt = hist[tid];
    sc[tid] = cnt;
    __syncthreads();
    for (int off = 1; off < 256; off <<= 1) {
        int t = (tid >= off) ? sc[tid - off] : 0;
        __syncthreads();
        sc[tid] += t;
        __syncthreads();
    }
    int excl = sc[tid] - cnt;
    cur[tid] = excl;
    rowp[b * 256 + tid] = e0 + excl;
    inv_si[b * 256 + tid] = rsqrtf((float)max(cnt, 1));
    if (b == 255 && tid == 255) rowp[65536] = N_EDGES;
    __syncthreads();
    for (int i = tid; i < nE; i += 256) {
        int2 e = (i < STCAP) ? staged[i] : bedges[e0 + i];
        int dl = (e.x >> 16) & 255;
        int pos = atomicAdd(&cur[dl], 1);
        csr[e0 + pos] = make_int2(e.x & 0xFFFF, e.y);
    }
}

// ---------------- dense: out[r][c] = sum_k f(in[r][k]) * W[k][c] ----------------
__global__ __launch_bounds__(256) void gemm_kernel(const float* __restrict__ in,
                                                   const float* __restrict__ W,
                                                   const float* __restrict__ inv_so,
                                                   const float* __restrict__ alpha,
                                                   const float* __restrict__ beta,
                                                   float* __restrict__ out) {
    __shared__ float wT[64][68];
    __shared__ float xlds[16][64];
    int tid = threadIdx.x;
#pragma unroll
    for (int j = 0; j < 16; ++j) {
        int i = j * 256 + tid;
        wT[i & 63][i >> 6] = W[i];
    }
    int r0 = blockIdx.x * 16;
#pragma unroll
    for (int j = 0; j < 4; ++j) {
        int i = j * 256 + tid;
        int r = i >> 6, k = i & 63;
        int gr = r0 + r;
        float v = in[(size_t)gr * 64 + k];
        if (alpha) v = alpha[k] * v + beta[k];
        xlds[r][k] = v * inv_so[gr];
    }
    __syncthreads();
    int c = tid & 63;
    int rg = tid >> 6;
    float acc[4] = {0.f, 0.f, 0.f, 0.f};
#pragma unroll
    for (int k0 = 0; k0 < 64; k0 += 4) {
        float4 wv = *(const float4*)&wT[c][k0];
#pragma unroll
        for (int j = 0; j < 4; ++j) {
            float4 xv = *(const float4*)&xlds[rg * 4 + j][k0];
            acc[j] += xv.x * wv.x + xv.y * wv.y + xv.z * wv.z + xv.w * wv.w;
        }
    }
#pragma unroll
    for (int j = 0; j < 4; ++j)
        out[(size_t)(r0 + rg * 4 + j) * 64 + c] = acc[j];
}

// ---------------- pull-aggregation + inv_si + LeakyReLU + fused stats/pool ----------------
// 16 lanes/node, float4/lane; unroll 8; epilogue: block stats partial (+pool atomics)
__global__ __launch_bounds__(256) void agg_kernel(const float4* __restrict__ T4,
                                                  const int* __restrict__ rowp,
                                                  const float* __restrict__ inv_si,
                                                  const int2* __restrict__ csr,
                                                  float4* __restrict__ Y4,
                                                  float4* __restrict__ statsP4,
                                                  float* __restrict__ pooledSum) {
    __shared__ float4 ls[256];
    __shared__ float4 lq[256];
    int tid = threadIdx.x;
    int node = blockIdx.x * 16 + (tid >> 4);
    int l16 = tid & 15;
    int start = rowp[node];
    int cnt = rowp[node + 1] - start;
    const int2* ep = csr + start;
    float4 acc = make_float4(0.f, 0.f, 0.f, 0.f);
    int i = 0;
    for (; i + 8 <= cnt; i += 8) {
        int2 e[8];
#pragma unroll
        for (int k = 0; k < 8; ++k) e[k] = ep[i + k];
        float4 a[8];
#pragma unroll
        for (int k = 0; k < 8; ++k) a[k] = T4[(size_t)e[k].x * 16 + l16];
#pragma unroll
        for (int k = 0; k < 8; ++k) {
            float w = __int_as_float(e[k].y);
            acc.x += a[k].x * w;
            acc.y += a[k].y * w;
            acc.z += a[k].z * w;
            acc.w += a[k].w * w;
        }
    }
    for (; i + 2 <= cnt; i += 2) {
        int2 e0 = ep[i], e1 = ep[i + 1];
        float4 a0 = T4[(size_t)e0.x * 16 + l16];
        float4 a1 = T4[(size_t)e1.x * 16 + l16];
        float w0 = __int_as_float(e0.y), w1 = __int_as_float(e1.y);
        acc.x += a0.x * w0 + a1.x * w1;
        acc.y += a0.y * w0 + a1.y * w1;
        acc.z += a0.z * w0 + a1.z * w1;
        acc.w += a0.w * w0 + a1.w * w1;
    }
    if (i < cnt) {
        int2 e = ep[i];
        float4 a = T4[(size_t)e.x * 16 + l16];
        float w = __int_as_float(e.y);
        acc.x += a.x * w; acc.y += a.y * w; acc.z += a.z * w; acc.w += a.w * w;
    }
    float s = inv_si[node];
    float4 v;
    v.x = acc.x * s; v.x = (v.x >= 0.f) ? v.x : SLOPE * v.x;
    v.y = acc.y * s; v.y = (v.y >= 0.f) ? v.y : SLOPE * v.y;
    v.z = acc.z * s; v.z = (v.z >= 0.f) ? v.z : SLOPE * v.z;
    v.w = acc.w * s; v.w = (v.w >= 0.f) ? v.w : SLOPE * v.w;
    Y4[(size_t)node * 16 + l16] = v;

    // fused stats (and pool) partials: reduce over the block's 16 nodes
    ls[tid] = v;
    lq[tid] = make_float4(v.x * v.x, v.y * v.y, v.z * v.z, v.w * v.w);
    __syncthreads();
    for (int off = 128; off >= 16; off >>= 1) {
        if (tid < off) {
            float4 a = ls[tid + off], b = lq[tid + off];
            ls[tid].x += a.x; ls[tid].y += a.y; ls[tid].z += a.z; ls[tid].w += a.w;
            lq[tid].x += b.x; lq[tid].y += b.y; lq[tid].z += b.z; lq[tid].w += b.w;
        }
        __syncthreads();
    }
    if (tid < 32)
        statsP4[blockIdx.x * 32 + tid] = (tid < 16) ? ls[tid] : lq[tid - 16];
    if (pooledSum && tid < 16) {
        int graph = blockIdx.x >> 7;   // 128 blocks per graph
        float4 a = ls[tid];
        atomicAdd(&pooledSum[graph * 64 + tid * 4 + 0], a.x);
        atomicAdd(&pooledSum[graph * 64 + tid * 4 + 1], a.y);
        atomicAdd(&pooledSum[graph * 64 + tid * 4 + 2], a.z);
        atomicAdd(&pooledSum[graph * 64 + tid * 4 + 3], a.w);
    }
}

// ---------------- reduce 4096x128 stats partials -> stats[128] ----------------
__global__ __launch_bounds__(256) void reduce_stats(const float* __restrict__ statsP,
                                                    float* __restrict__ stats) {
    __shared__ float red[256];
    int tid = threadIdx.x, b = blockIdx.x;   // grid 64
    int col = tid & 127, half = tid >> 7;
    float s = 0.f;
    for (int i = half; i < 64; i += 2)
        s += statsP[(size_t)(b * 64 + i) * 128 + col];
    red[tid] = s;
    __syncthreads();
    if (tid < 128) atomicAdd(&stats[col], red[tid] + red[tid + 128]);
}

// GraphNorm(y) = alpha*y + beta
__global__ void finalize_kernel(const float* __restrict__ Sy, const float* __restrict__ Syy,
                                const float* __restrict__ w, const float* __restrict__ b,
                                const float* __restrict__ a,
                                float* __restrict__ alpha, float* __restrict__ beta) {
    int f = threadIdx.x;
    if (f < 64) {
        float m = Sy[f] * (1.f / N_NODES);
        float q = Syy[f] * (1.f / N_NODES);
        float af = a[f];
        float var = q - 2.f * af * m * m + af * af * m * m;
        float stdv = sqrtf(var + EPS_GN);
        float al = w[f] / stdv;
        alpha[f] = al;
        beta[f] = b[f] - al * af * m;
    }
}

// ---------------- final: GN2 finalize + affine on pooled mean + @ Wc^T ----------------
__global__ __launch_bounds__(256) void out_kernel(const float* __restrict__ stats2,
                                                  const float* __restrict__ gn_w,
                                                  const float* __restrict__ gn_b,
                                                  const float* __restrict__ gn_a,
                                                  const float* __restrict__ pooledSum,
                                                  const float* __restrict__ Wc,
                                                  float* __restrict__ out) {
    __shared__ float al[64], be[64];
    __shared__ float p[B_GRAPHS * 64];
    int tid = threadIdx.x;
    if (tid < 64) {
        float m = stats2[tid] * (1.f / N_NODES);
        float q = stats2[64 + tid] * (1.f / N_NODES);
        float af = gn_a[tid];
        float var = q - 2.f * af * m * m + af * af * m * m;
        float a_ = gn_w[tid] / sqrtf(var + EPS_GN);
        al[tid] = a_;
        be[tid] = gn_b[tid] - a_ * af * m;
    }
    __syncthreads();
    for (int i = tid; i < B_GRAPHS * 64; i += 256) {
        int f = i & 63;
        p[i] = al[f] * (pooledSum[i] * (1.f / NPG)) + be[f];
    }
    __syncthreads();
    for (int idx = tid; idx < B_GRAPHS * 32; idx += 256) {
        int g = idx >> 5, o = idx & 31;
        float acc = 0.f;
        for (int f = 0; f < 64; ++f)
            acc += p[g * 64 + f] * Wc[o * 64 + f];
        out[idx] = acc;
    }
}

extern "C" void kernel_launch(void* const* d_in, const int* in_sizes, int n_in,
                              void* d_out, int out_size, void* d_ws, size_t ws_size,
                              hipStream_t stream) {
    const float* x     = (const float*)d_in[0];
    const float* ew    = (const float*)d_in[1];
    const float* W1    = (const float*)d_in[2];
    const float* W2    = (const float*)d_in[3];
    const float* Wc    = (const float*)d_in[4];
    const float* gn1_w = (const float*)d_in[5];
    const float* gn1_b = (const float*)d_in[6];
    const float* gn1_a = (const float*)d_in[7];
    const float* gn2_w = (const float*)d_in[8];
    const float* gn2_b = (const float*)d_in[9];
    const float* gn2_a = (const float*)d_in[10];
    const int* src     = (const int*)d_in[11];
    const int* dst     = (const int*)d_in[12];

    char* ws = (char*)d_ws;
    int*   coarse     = (int*)(ws + 0);             // 1 KB   [memset]
    float* stats1     = (float*)(ws + 1024);        // 512 B  [memset]
    float* stats2     = (float*)(ws + 1536);        // 512 B  [memset]
    float* pooledSum  = (float*)(ws + 2048);        // 8 KB   [memset]
    float* ab1        = (float*)(ws + 10240);       // 512 B
    int*   bucketBase = (int*)(ws + 11264);         // 257 ints
    int*   cursor     = (int*)(ws + 12544);         // 1 KB
    int*   rowp       = (int*)(ws + 16384);         // 65537 ints (~256 KB)
    float* inv_so     = (float*)(ws + 294912);      // 256 KB
    float* inv_si     = (float*)(ws + 557056);      // 256 KB
    unsigned int* partial = (unsigned int*)(ws + (1u << 20)); // 4 MB (dead after reduce_src)
    int2*  csr        = (int2*)(ws + (1u << 20));   // 8 MB (overlaps partial)
    int2*  bedges     = (int2*)(ws + (9u << 20));   // 8 MB
    float* bufA       = (float*)(ws + (17u << 20)); // 16 MB
    float* bufB       = (float*)(ws + (33u << 20)); // 16 MB
    float* statsP     = (float*)(ws + (49u << 20)); // 2 MB (4096 x 128)

    hipMemsetAsync(ws, 0, 10240, stream);

    // graph structure (recomputed each call)
    coarse_hist<<<64, 256, 0, stream>>>((const int4*)dst, coarse);
    src_hist<<<64, 256, 0, stream>>>((const int4*)src, partial);
    scan_coarse<<<1, 256, 0, stream>>>(coarse, bucketBase, cursor);
    reduce_src<<<64, 256, 0, stream>>>(partial, (float4*)inv_so);
    bucket_scatter<<<256, 256, 0, stream>>>((const int4*)src, (const int4*)dst,
                                            (const float4*)ew, cursor, bedges);
    refine_kernel<<<NBUCKET, 256, 0, stream>>>(bedges, bucketBase, rowp, inv_si, csr);

    // layer 1
    gemm_kernel<<<N_NODES / 16, 256, 0, stream>>>(x, W1, inv_so, nullptr, nullptr, bufA);
    agg_kernel<<<N_NODES / 16, 256, 0, stream>>>((const float4*)bufA, rowp, inv_si, csr,
                                                 (float4*)bufB, (float4*)statsP, nullptr);
    reduce_stats<<<64, 256, 0, stream>>>(statsP, stats1);
    finalize_kernel<<<1, 64, 0, stream>>>(stats1, stats1 + 64, gn1_w, gn1_b, gn1_a,
                                          ab1 + 0, ab1 + 64);

    // layer 2 (GraphNorm-1 affine fused into GEMM2 load; stats+pool fused into agg)
    gemm_kernel<<<N_NODES / 16, 256, 0, stream>>>(bufB, W2, inv_so, ab1 + 0, ab1 + 64, bufA);
    agg_kernel<<<N_NODES / 16, 256, 0, stream>>>((const float4*)bufA, rowp, inv_si, csr,
                                                 (float4*)bufB, (float4*)statsP, pooledSum);
    reduce_stats<<<64, 256, 0, stream>>>(statsP, stats2);

    // GN2 finalize + pooled affine + classifier (single block)
    out_kernel<<<1, 256, 0, stream>>>(stats2, gn2_w, gn2_b, gn2_a, pooledSum, Wc,
                                      (float*)d_out);
}